// Round 3
// baseline (285.560 us; speedup 1.0000x reference)
//
#include <hip/hip_runtime.h>
#include <hip/hip_cooperative_groups.h>

namespace cg = cooperative_groups;

#define BB 64
#define LL 512
#define DD 300
#define CC 128
#define NBLK 512
#define NTHR 256

// Single fused cooperative kernel.
// Phase 1 (all 512 blocks): weighted embedding gather into per-(block,half)
//   partials Gpart[b][p][kk][d] (p = tc*2+sub, 16 partials per b) — no
//   atomics, no pre-zero needed (every slot fully overwritten).
// Phase 2 (blocks 0..191): reduce 16 partials -> sG, then
//   hT[(kk*128+c')*64+b] = <conv_w[c'],sG> + conv_b[c']*S_k + b_k
// Phase 3 (blocks 0..127): out[b,c] = sum_j fcw[c,j]*hT[j,b] + fcb[c]
__global__ __launch_bounds__(NTHR, 2) void fused(
    const int* __restrict__ x, const float* __restrict__ embed,
    const float* __restrict__ conv_w, const float* __restrict__ conv_b,
    const float* __restrict__ w3, const float* __restrict__ b3,
    const float* __restrict__ w4, const float* __restrict__ b4,
    const float* __restrict__ w5, const float* __restrict__ b5,
    const float* __restrict__ fcw, const float* __restrict__ fcb,
    float* __restrict__ Gpart, float* __restrict__ hT,
    float* __restrict__ out) {
  cg::grid_group grid = cg::this_grid();
  const int blk = blockIdx.x;
  const int tid = threadIdx.x;

  __shared__ int sx[64];
  __shared__ float su[3][64];
  __shared__ __align__(16) float sG[DD];
  __shared__ float red[NTHR];

  // ------------------------------ Phase 1 ------------------------------
  {
    const int b = blk >> 3;     // batch
    const int tc = blk & 7;     // token chunk of 64
    const int sub = tid >> 7;   // half-block handles 32 tokens
    const int stid = tid & 127; // float2 slot {stid, 128+stid(<150)}

    if (tid < 64) {
      const int t = tc * 64 + tid;
      sx[tid] = x[b * LL + t];
      const float* ws[3] = {w3, w4, w5};
#pragma unroll
      for (int kk = 0; kk < 3; ++kk) {
        const int k = kk + 3;
        int lo = t - k + 1; if (lo < 0) lo = 0;
        int hi = t; const int lim = LL - k - 1; if (hi > lim) hi = lim;
        float s = 0.f;
        for (int l = lo; l <= hi; ++l) s += ws[kk][l];
        su[kk][tid] = s;
      }
    }
    __syncthreads();

    float a0x = 0.f, a0y = 0.f, a1x = 0.f, a1y = 0.f, a2x = 0.f, a2y = 0.f;
    float c0x = 0.f, c0y = 0.f, c1x = 0.f, c1y = 0.f, c2x = 0.f, c2y = 0.f;
    const bool tail = stid < (DD / 2 - 128);  // slots 128..149 -> 22 lanes

#pragma unroll 4
    for (int i = 0; i < 32; ++i) {
      const int j = sub * 32 + i;
      const float2* rp = (const float2*)(embed + (size_t)sx[j] * DD);
      const float2 v = rp[stid];
      const float w0 = su[0][j], w1 = su[1][j], w2 = su[2][j];
      a0x += w0 * v.x; a0y += w0 * v.y;
      a1x += w1 * v.x; a1y += w1 * v.y;
      a2x += w2 * v.x; a2y += w2 * v.y;
      if (tail) {
        const float2 v2 = rp[128 + stid];
        c0x += w0 * v2.x; c0y += w0 * v2.y;
        c1x += w1 * v2.x; c1y += w1 * v2.y;
        c2x += w2 * v2.x; c2y += w2 * v2.y;
      }
    }

    const int p = tc * 2 + sub;
    float* Gp = Gpart + ((size_t)(b * 16 + p) * 3) * DD;
    const int d0 = 2 * stid;
    Gp[0 * DD + d0] = a0x; Gp[0 * DD + d0 + 1] = a0y;
    Gp[1 * DD + d0] = a1x; Gp[1 * DD + d0 + 1] = a1y;
    Gp[2 * DD + d0] = a2x; Gp[2 * DD + d0 + 1] = a2y;
    if (tail) {
      const int d1 = 2 * (128 + stid);
      Gp[0 * DD + d1] = c0x; Gp[0 * DD + d1 + 1] = c0y;
      Gp[1 * DD + d1] = c1x; Gp[1 * DD + d1 + 1] = c1y;
      Gp[2 * DD + d1] = c2x; Gp[2 * DD + d1 + 1] = c2y;
    }
  }

  grid.sync();

  // ------------------------------ Phase 2 ------------------------------
  if (blk < 3 * BB) {
    const int b = blk / 3;
    const int kk = blk % 3;

    for (int d = tid; d < DD; d += NTHR) {
      const float* gp = Gpart + ((size_t)(b * 48) + kk) * DD + d;
      float s = 0.f;
#pragma unroll
      for (int p = 0; p < 16; ++p) s += gp[(size_t)p * 3 * DD];
      sG[d] = s;
    }

    const float* wk = (kk == 0) ? w3 : ((kk == 1) ? w4 : w5);
    const float* bk = (kk == 0) ? b3 : ((kk == 1) ? b4 : b5);
    const int len = LL - (kk + 3);
    float s = 0.f;
    for (int j = tid; j < len; j += NTHR) s += wk[j];
    red[tid] = s;
    __syncthreads();
    for (int off = NTHR / 2; off >= 1; off >>= 1) {
      if (tid < off) red[tid] += red[tid + off];
      __syncthreads();
    }
    const float Sk = red[0];
    const float bkv = bk[0];
    const float2* sG2 = (const float2*)sG;
    const int lane = tid & 63;
    const int wid = tid >> 6;

    for (int m = 0; m < 32; ++m) {
      const int cp = wid * 32 + m;
      const float2* cwp = (const float2*)(conv_w + cp * DD);  // 150 float2
      float acc = 0.f;
      {
        const float2 v = cwp[lane];
        const float2 g = sG2[lane];
        acc += v.x * g.x + v.y * g.y;
      }
      {
        const float2 v = cwp[lane + 64];
        const float2 g = sG2[lane + 64];
        acc += v.x * g.x + v.y * g.y;
      }
      if (lane < 22) {
        const float2 v = cwp[lane + 128];
        const float2 g = sG2[lane + 128];
        acc += v.x * g.x + v.y * g.y;
      }
#pragma unroll
      for (int off = 32; off >= 1; off >>= 1) acc += __shfl_down(acc, off, 64);
      if (lane == 0) {
        hT[(kk * CC + cp) * BB + b] = acc + conv_b[cp] * Sk + bkv;
      }
    }
  }

  grid.sync();

  // ------------------------------ Phase 3 ------------------------------
  if (blk < CC && tid < BB) {
    const int c = blk;
    const int lane = tid;  // = b
    const float4* row4 = (const float4*)(fcw + c * (3 * CC));  // 96 float4
    float acc0 = 0.f, acc1 = 0.f, acc2 = 0.f, acc3 = 0.f;
#pragma unroll 4
    for (int j4 = 0; j4 < (3 * CC) / 4; ++j4) {
      const float4 w = row4[j4];
      const int j = 4 * j4;
      acc0 += w.x * hT[(j + 0) * BB + lane];
      acc1 += w.y * hT[(j + 1) * BB + lane];
      acc2 += w.z * hT[(j + 2) * BB + lane];
      acc3 += w.w * hT[(j + 3) * BB + lane];
    }
    out[lane * CC + c] = (acc0 + acc1) + (acc2 + acc3) + fcb[c];
  }
}

// ---------------------------------------------------------------------------
extern "C" void kernel_launch(void* const* d_in, const int* in_sizes, int n_in,
                              void* d_out, int out_size, void* d_ws,
                              size_t ws_size, hipStream_t stream) {
  const int* x = (const int*)d_in[0];
  const float* embed = (const float*)d_in[1];
  const float* conv_w = (const float*)d_in[2];
  const float* conv_b = (const float*)d_in[3];
  const float* fc3w = (const float*)d_in[4];
  const float* fc3b = (const float*)d_in[5];
  const float* fc4w = (const float*)d_in[6];
  const float* fc4b = (const float*)d_in[7];
  const float* fc5w = (const float*)d_in[8];
  const float* fc5b = (const float*)d_in[9];
  const float* fcw = (const float*)d_in[10];
  const float* fcb = (const float*)d_in[11];

  float* Gpart = (float*)d_ws;                    // 64*16*3*300 = 921600 f32
  float* hT = Gpart + (size_t)BB * 16 * 3 * DD;   // 384*64 f32
  float* outp = (float*)d_out;

  void* args[] = {
      (void*)&x,    (void*)&embed, (void*)&conv_w, (void*)&conv_b,
      (void*)&fc3w, (void*)&fc3b,  (void*)&fc4w,   (void*)&fc4b,
      (void*)&fc5w, (void*)&fc5b,  (void*)&fcw,    (void*)&fcb,
      (void*)&Gpart, (void*)&hT,   (void*)&outp};

  hipLaunchCooperativeKernel((void*)fused, dim3(NBLK), dim3(NTHR), args, 0,
                             stream);
}

// Round 4
// 196.982 us; speedup vs baseline: 1.4497x; 1.4497x over previous
//
#include <hip/hip_runtime.h>
#include <stdint.h>

#define BB 64
#define LL 512
#define DD 300
#define CC 128

// ---------------------------------------------------------------------------
// Kernel 1: weighted embedding gather into per-block partials (no atomics,
// no pre-zero — every slot fully overwritten).
//   Gpart[b][p][kk][d] = sum_{t in chunk p} u_k[t] * embed[x[b,t]][d]
// u_k[t] = sum of wk[l] over valid windows covering token t (<=5 terms).
// Grid: (b, tc) = 64*16 = 1024 blocks of 256 threads (4 waves/SIMD TLP).
// Each half-block (sub) handles 16 tokens; thread owns float2 slots
// {stid, 128+stid(<150)}; rows read coalesced (512 B/wave/load), unroll 8
// for many outstanding loads.
// ---------------------------------------------------------------------------
__global__ __launch_bounds__(256) void k_gather(
    const int* __restrict__ x, const float* __restrict__ embed,
    const float* __restrict__ w3, const float* __restrict__ w4,
    const float* __restrict__ w5, float* __restrict__ Gpart) {
  const int b = blockIdx.x >> 4;
  const int tc = blockIdx.x & 15;
  const int tid = threadIdx.x;
  const int sub = tid >> 7;    // half-block: 16 tokens each
  const int stid = tid & 127;  // float2 slot

  __shared__ int sx[32];
  __shared__ float su[3][32];

  if (tid < 32) {
    const int t = tc * 32 + tid;
    sx[tid] = x[b * LL + t];
    const float* ws[3] = {w3, w4, w5};
#pragma unroll
    for (int kk = 0; kk < 3; ++kk) {
      const int k = kk + 3;
      int lo = t - k + 1; if (lo < 0) lo = 0;
      int hi = t; const int lim = LL - k - 1; if (hi > lim) hi = lim;
      float s = 0.f;
      for (int l = lo; l <= hi; ++l) s += ws[kk][l];
      su[kk][tid] = s;
    }
  }
  __syncthreads();

  float a0x = 0.f, a0y = 0.f, a1x = 0.f, a1y = 0.f, a2x = 0.f, a2y = 0.f;
  float c0x = 0.f, c0y = 0.f, c1x = 0.f, c1y = 0.f, c2x = 0.f, c2y = 0.f;
  const bool tail = stid < (DD / 2 - 128);  // slots 128..149 -> 22 lanes

#pragma unroll 8
  for (int i = 0; i < 16; ++i) {
    const int j = sub * 16 + i;
    const float2* rp = (const float2*)(embed + (size_t)sx[j] * DD);
    const float2 v = rp[stid];
    const float w0 = su[0][j], w1 = su[1][j], w2 = su[2][j];
    a0x += w0 * v.x; a0y += w0 * v.y;
    a1x += w1 * v.x; a1y += w1 * v.y;
    a2x += w2 * v.x; a2y += w2 * v.y;
    if (tail) {
      const float2 v2 = rp[128 + stid];
      c0x += w0 * v2.x; c0y += w0 * v2.y;
      c1x += w1 * v2.x; c1y += w1 * v2.y;
      c2x += w2 * v2.x; c2y += w2 * v2.y;
    }
  }

  const int p = tc * 2 + sub;  // 0..31
  float* Gp = Gpart + (size_t)(b * 32 + p) * (3 * DD);
  const int d0 = 2 * stid;
  Gp[0 * DD + d0] = a0x; Gp[0 * DD + d0 + 1] = a0y;
  Gp[1 * DD + d0] = a1x; Gp[1 * DD + d0 + 1] = a1y;
  Gp[2 * DD + d0] = a2x; Gp[2 * DD + d0 + 1] = a2y;
  if (tail) {
    const int d1 = 2 * (128 + stid);
    Gp[0 * DD + d1] = c0x; Gp[0 * DD + d1 + 1] = c0y;
    Gp[1 * DD + d1] = c1x; Gp[1 * DD + d1 + 1] = c1y;
    Gp[2 * DD + d1] = c2x; Gp[2 * DD + d1 + 1] = c2y;
  }
}

// ---------------------------------------------------------------------------
// Kernel 2: per-batch head — partial reduce + sim GEMV + final FC fused.
// One block per b (64 blocks of 256 = 4 waves). All of h[b,384] is
// block-local, so the FC folds in with no extra kernel.
//   sG[kk*300+d] = sum_p Gpart[b][p][kk][d]            (float4 loads)
//   h[kk*128+cp] = <conv_w[cp], sG[kk]> + conv_b[cp]*S_k + b_k
//   out[b,c]     = sum_j fcw[c,j]*h[j] + fcb[c]
// ---------------------------------------------------------------------------
__global__ __launch_bounds__(256) void k_head(
    const float* __restrict__ Gpart, const float* __restrict__ conv_w,
    const float* __restrict__ conv_b,
    const float* __restrict__ w3, const float* __restrict__ b3,
    const float* __restrict__ w4, const float* __restrict__ b4,
    const float* __restrict__ w5, const float* __restrict__ b5,
    const float* __restrict__ fcw, const float* __restrict__ fcb,
    float* __restrict__ out) {
  const int b = blockIdx.x;
  const int tid = threadIdx.x;
  const int lane = tid & 63;
  const int wid = tid >> 6;

  __shared__ __align__(16) float sG[3 * DD];  // 900
  __shared__ float sh[3 * CC];                // 384
  __shared__ float red[256];
  __shared__ float sSk[3];

  // A: reduce 32 partials (900 floats = 225 float4 slots).
  {
    const float4* gb4 = (const float4*)(Gpart + (size_t)b * 32 * (3 * DD));
    float4* sG4 = (float4*)sG;
    if (tid < 225) {
      float4 s0 = gb4[tid];
      float4 s1 = gb4[225 + tid];
#pragma unroll
      for (int p = 2; p < 32; p += 2) {
        const float4 v0 = gb4[p * 225 + tid];
        const float4 v1 = gb4[(p + 1) * 225 + tid];
        s0.x += v0.x; s0.y += v0.y; s0.z += v0.z; s0.w += v0.w;
        s1.x += v1.x; s1.y += v1.y; s1.z += v1.z; s1.w += v1.w;
      }
      s0.x += s1.x; s0.y += s1.y; s0.z += s1.z; s0.w += s1.w;
      sG4[tid] = s0;
    }
  }

  // B: S_k = sum of wk (len 509/508/507).
  {
    const float* ws[3] = {w3, w4, w5};
#pragma unroll
    for (int kk = 0; kk < 3; ++kk) {
      const int len = LL - (kk + 3);
      float s = (tid < len) ? ws[kk][tid] : 0.f;
      if (tid + 256 < len) s += ws[kk][tid + 256];
      red[tid] = s;
      __syncthreads();
      for (int off = 128; off >= 1; off >>= 1) {
        if (tid < off) red[tid] += red[tid + off];
        __syncthreads();
      }
      if (tid == 0) sSk[kk] = red[0];
      __syncthreads();
    }
  }
  // (barriers in B also publish sG to all waves)

  // C: sim GEMV — 384 outputs, wave w computes j = w*96 + m.
  const float bks[3] = {b3[0], b4[0], b5[0]};
  const float2* sG2 = (const float2*)sG;
#pragma unroll 2
  for (int m = 0; m < 96; ++m) {
    const int j = wid * 96 + m;
    const int kk = j >> 7;
    const int cp = j & 127;
    const float2* cwp = (const float2*)(conv_w + cp * DD);  // 150 float2
    const float2* g2 = sG2 + kk * 150;
    float acc;
    {
      const float2 v = cwp[lane];
      const float2 g = g2[lane];
      acc = v.x * g.x + v.y * g.y;
    }
    {
      const float2 v = cwp[lane + 64];
      const float2 g = g2[lane + 64];
      acc += v.x * g.x + v.y * g.y;
    }
    if (lane < 22) {
      const float2 v = cwp[lane + 128];
      const float2 g = g2[lane + 128];
      acc += v.x * g.x + v.y * g.y;
    }
#pragma unroll
    for (int off = 32; off >= 1; off >>= 1) acc += __shfl_down(acc, off, 64);
    if (lane == 0) sh[j] = acc + conv_b[cp] * sSk[kk] + bks[kk];
  }
  __syncthreads();

  // D: FC — 128 outputs, wave w computes c = w*32 + m (384 = 6*64).
#pragma unroll 2
  for (int m = 0; m < 32; ++m) {
    const int c = wid * 32 + m;
    const float* fr = fcw + c * (3 * CC);
    float acc = 0.f;
#pragma unroll
    for (int s = 0; s < 6; ++s) acc += fr[s * 64 + lane] * sh[s * 64 + lane];
#pragma unroll
    for (int off = 32; off >= 1; off >>= 1) acc += __shfl_down(acc, off, 64);
    if (lane == 0) out[b * CC + c] = acc + fcb[c];
  }
}

// ---------------------------------------------------------------------------
extern "C" void kernel_launch(void* const* d_in, const int* in_sizes, int n_in,
                              void* d_out, int out_size, void* d_ws,
                              size_t ws_size, hipStream_t stream) {
  const int* x = (const int*)d_in[0];
  const float* embed = (const float*)d_in[1];
  const float* conv_w = (const float*)d_in[2];
  const float* conv_b = (const float*)d_in[3];
  const float* fc3w = (const float*)d_in[4];
  const float* fc3b = (const float*)d_in[5];
  const float* fc4w = (const float*)d_in[6];
  const float* fc4b = (const float*)d_in[7];
  const float* fc5w = (const float*)d_in[8];
  const float* fc5b = (const float*)d_in[9];
  const float* fcw = (const float*)d_in[10];
  const float* fcb = (const float*)d_in[11];

  float* Gpart = (float*)d_ws;  // 64*32*3*300 f32 = 7.37 MB

  k_gather<<<dim3(BB * 16), dim3(256), 0, stream>>>(x, embed, fc3w, fc4w,
                                                    fc5w, Gpart);
  k_head<<<dim3(BB), dim3(256), 0, stream>>>(Gpart, conv_w, conv_b, fc3w,
                                             fc3b, fc4w, fc4b, fc5w, fc5b,
                                             fcw, fcb, (float*)d_out);
}

// Round 5
// 131.992 us; speedup vs baseline: 2.1635x; 1.4924x over previous
//
#include <hip/hip_runtime.h>
#include <stdint.h>

#define BB 64
#define LL 512
#define DD 300
#define CC 128

// ws layout (floats):
//   Gpart : [64][32][900]   = 1,843,200
//   Gred  : [64][900]       =    57,600   (float4-viewed: [64][225])
//   hT    : [64][384]       =    24,576   (b-major so k_fc reads coalesce)
//   skbk  : [8]  (Sk[0..2], bk[0..2])
#define OFF_GRED  (BB * 32 * 3 * DD)
#define OFF_HT    (OFF_GRED + BB * 3 * DD)
#define OFF_SKBK  (OFF_HT + BB * 3 * CC)

// ---------------------------------------------------------------------------
// Kernel 1 (unchanged from R4): weighted embedding gather into per-block
// partials. Gpart[b][p][kk][d] = sum_{t in chunk p} u_k[t]*embed[x[b,t]][d].
// Grid 1024 x 256.
// ---------------------------------------------------------------------------
__global__ __launch_bounds__(256) void k_gather(
    const int* __restrict__ x, const float* __restrict__ embed,
    const float* __restrict__ w3, const float* __restrict__ w4,
    const float* __restrict__ w5, float* __restrict__ Gpart) {
  const int b = blockIdx.x >> 4;
  const int tc = blockIdx.x & 15;
  const int tid = threadIdx.x;
  const int sub = tid >> 7;    // half-block: 16 tokens each
  const int stid = tid & 127;  // float2 slot

  __shared__ int sx[32];
  __shared__ float su[3][32];

  if (tid < 32) {
    const int t = tc * 32 + tid;
    sx[tid] = x[b * LL + t];
    const float* ws[3] = {w3, w4, w5};
#pragma unroll
    for (int kk = 0; kk < 3; ++kk) {
      const int k = kk + 3;
      int lo = t - k + 1; if (lo < 0) lo = 0;
      int hi = t; const int lim = LL - k - 1; if (hi > lim) hi = lim;
      float s = 0.f;
      for (int l = lo; l <= hi; ++l) s += ws[kk][l];
      su[kk][tid] = s;
    }
  }
  __syncthreads();

  float a0x = 0.f, a0y = 0.f, a1x = 0.f, a1y = 0.f, a2x = 0.f, a2y = 0.f;
  float c0x = 0.f, c0y = 0.f, c1x = 0.f, c1y = 0.f, c2x = 0.f, c2y = 0.f;
  const bool tail = stid < (DD / 2 - 128);  // slots 128..149 -> 22 lanes

#pragma unroll 8
  for (int i = 0; i < 16; ++i) {
    const int j = sub * 16 + i;
    const float2* rp = (const float2*)(embed + (size_t)sx[j] * DD);
    const float2 v = rp[stid];
    const float w0 = su[0][j], w1 = su[1][j], w2 = su[2][j];
    a0x += w0 * v.x; a0y += w0 * v.y;
    a1x += w1 * v.x; a1y += w1 * v.y;
    a2x += w2 * v.x; a2y += w2 * v.y;
    if (tail) {
      const float2 v2 = rp[128 + stid];
      c0x += w0 * v2.x; c0y += w0 * v2.y;
      c1x += w1 * v2.x; c1y += w1 * v2.y;
      c2x += w2 * v2.x; c2y += w2 * v2.y;
    }
  }

  const int p = tc * 2 + sub;  // 0..31
  float* Gp = Gpart + (size_t)(b * 32 + p) * (3 * DD);
  const int d0 = 2 * stid;
  Gp[0 * DD + d0] = a0x; Gp[0 * DD + d0 + 1] = a0y;
  Gp[1 * DD + d0] = a1x; Gp[1 * DD + d0 + 1] = a1y;
  Gp[2 * DD + d0] = a2x; Gp[2 * DD + d0 + 1] = a2y;
  if (tail) {
    const int d1 = 2 * (128 + stid);
    Gp[0 * DD + d1] = c0x; Gp[0 * DD + d1 + 1] = c0y;
    Gp[1 * DD + d1] = c1x; Gp[1 * DD + d1 + 1] = c1y;
    Gp[2 * DD + d1] = c2x; Gp[2 * DD + d1 + 1] = c2y;
  }
}

// ---------------------------------------------------------------------------
// Kernel 2: partial reduction (thread-per-float4, 14400 outputs; blocks 0..56)
// + S_k/b_k computation (blocks 57..59).
// ---------------------------------------------------------------------------
__global__ __launch_bounds__(256) void k_reduce(
    const float* __restrict__ Gpart,
    const float* __restrict__ w3, const float* __restrict__ b3,
    const float* __restrict__ w4, const float* __restrict__ b4,
    const float* __restrict__ w5, const float* __restrict__ b5,
    float* __restrict__ Gred, float* __restrict__ skbk) {
  __shared__ float red[256];
  const int blk = blockIdx.x;
  const int tid = threadIdx.x;

  if (blk < 57) {
    const int idx = blk * 256 + tid;  // float4 output id, < 14400
    if (idx < BB * 225) {
      const int b = idx / 225;
      const int q = idx - b * 225;
      const float4* gp = (const float4*)Gpart + (size_t)b * 32 * 225 + q;
      float4 s0 = gp[0];
      float4 s1 = gp[225];
#pragma unroll
      for (int p = 2; p < 32; p += 2) {
        const float4 v0 = gp[(size_t)p * 225];
        const float4 v1 = gp[(size_t)(p + 1) * 225];
        s0.x += v0.x; s0.y += v0.y; s0.z += v0.z; s0.w += v0.w;
        s1.x += v1.x; s1.y += v1.y; s1.z += v1.z; s1.w += v1.w;
      }
      s0.x += s1.x; s0.y += s1.y; s0.z += s1.z; s0.w += s1.w;
      ((float4*)Gred)[idx] = s0;
    }
  } else {
    const int kk = blk - 57;
    const float* wk = (kk == 0) ? w3 : ((kk == 1) ? w4 : w5);
    const float* bk = (kk == 0) ? b3 : ((kk == 1) ? b4 : b5);
    const int len = LL - (kk + 3);
    float s = (tid < len) ? wk[tid] : 0.f;
    if (tid + 256 < len) s += wk[tid + 256];
    red[tid] = s;
    __syncthreads();
    for (int off = 128; off >= 1; off >>= 1) {
      if (tid < off) red[tid] += red[tid + off];
      __syncthreads();
    }
    if (tid == 0) { skbk[kk] = red[0]; skbk[3 + kk] = bk[0]; }
  }
}

// ---------------------------------------------------------------------------
// Kernel 3: sim GEMV — one wave per output o = b*384 + j  (24576 outputs).
// Grid 6144 x 256 (4 waves/block). conv_w (154 KB) and Gred (230 KB) are
// L2-resident; all reads coalesced per wave; 6-shfl reduce.
//   hT[b*384 + j] = <conv_w[cp], Gred[b][kk]> + conv_b[cp]*Sk[kk] + bk[kk]
// ---------------------------------------------------------------------------
__global__ __launch_bounds__(256) void k_sim(
    const float* __restrict__ Gred, const float* __restrict__ conv_w,
    const float* __restrict__ conv_b, const float* __restrict__ skbk,
    float* __restrict__ hT) {
  const int o = blockIdx.x * 4 + (threadIdx.x >> 6);
  const int lane = threadIdx.x & 63;
  const int b = o / 384;
  const int j = o - b * 384;
  const int kk = j >> 7;
  const int cp = j & 127;

  const float2* cwp = (const float2*)(conv_w + cp * DD);        // 150 float2
  const float2* g2 = (const float2*)(Gred + (b * 3 + kk) * DD); // 150 float2

  float acc;
  {
    const float2 v = cwp[lane];
    const float2 g = g2[lane];
    acc = v.x * g.x + v.y * g.y;
  }
  {
    const float2 v = cwp[lane + 64];
    const float2 g = g2[lane + 64];
    acc += v.x * g.x + v.y * g.y;
  }
  if (lane < 22) {
    const float2 v = cwp[lane + 128];
    const float2 g = g2[lane + 128];
    acc += v.x * g.x + v.y * g.y;
  }
#pragma unroll
  for (int off = 32; off >= 1; off >>= 1) acc += __shfl_down(acc, off, 64);
  if (lane == 0) {
    hT[b * (3 * CC) + j] = acc + conv_b[cp] * skbk[kk] + skbk[3 + kk];
  }
}

// ---------------------------------------------------------------------------
// Kernel 4: final FC — one wave per output o = b*128 + c  (8192 outputs).
// Grid 2048 x 256. hT is [b][j]-major and fcw rows are j-major, so both
// reads coalesce across lanes (6 segments of 64).
//   out[b,c] = sum_j fcw[c,j]*hT[b,j] + fcb[c]
// ---------------------------------------------------------------------------
__global__ __launch_bounds__(256) void k_fc(
    const float* __restrict__ hT, const float* __restrict__ fcw,
    const float* __restrict__ fcb, float* __restrict__ out) {
  const int o = blockIdx.x * 4 + (threadIdx.x >> 6);
  const int lane = threadIdx.x & 63;
  const int b = o >> 7;
  const int c = o & 127;

  const float* fr = fcw + c * (3 * CC);
  const float* hr = hT + b * (3 * CC);
  float acc = 0.f;
#pragma unroll
  for (int s = 0; s < 6; ++s) acc += fr[s * 64 + lane] * hr[s * 64 + lane];
#pragma unroll
  for (int off = 32; off >= 1; off >>= 1) acc += __shfl_down(acc, off, 64);
  if (lane == 0) out[b * CC + c] = acc + fcb[c];
}

// ---------------------------------------------------------------------------
extern "C" void kernel_launch(void* const* d_in, const int* in_sizes, int n_in,
                              void* d_out, int out_size, void* d_ws,
                              size_t ws_size, hipStream_t stream) {
  const int* x = (const int*)d_in[0];
  const float* embed = (const float*)d_in[1];
  const float* conv_w = (const float*)d_in[2];
  const float* conv_b = (const float*)d_in[3];
  const float* fc3w = (const float*)d_in[4];
  const float* fc3b = (const float*)d_in[5];
  const float* fc4w = (const float*)d_in[6];
  const float* fc4b = (const float*)d_in[7];
  const float* fc5w = (const float*)d_in[8];
  const float* fc5b = (const float*)d_in[9];
  const float* fcw = (const float*)d_in[10];
  const float* fcb = (const float*)d_in[11];

  float* Gpart = (float*)d_ws;
  float* Gred = Gpart + OFF_GRED;
  float* hT = (float*)d_ws + OFF_HT;
  float* skbk = (float*)d_ws + OFF_SKBK;

  k_gather<<<dim3(BB * 16), dim3(256), 0, stream>>>(x, embed, fc3w, fc4w,
                                                    fc5w, Gpart);
  k_reduce<<<dim3(60), dim3(256), 0, stream>>>(Gpart, fc3w, fc3b, fc4w, fc4b,
                                               fc5w, fc5b, Gred, skbk);
  k_sim<<<dim3(6144), dim3(256), 0, stream>>>(Gred, conv_w, conv_b, skbk, hT);
  k_fc<<<dim3(2048), dim3(256), 0, stream>>>(hT, fcw, fcb, (float*)d_out);
}